// Round 1
// baseline (36920.639 us; speedup 1.0000x reference)
//
#include <hip/hip_runtime.h>
#include <cstddef>

// ---------------- problem constants ----------------
#define NHID 1024
#define NVOC 31
#define NB   64
#define NSEQ 512
#define NBLK 192     // 64 A + 64 B + 64 C workgroups (<=256 CUs -> co-resident)
#define NTHR 512     // 8 waves
#define EPSV 1e-5f
#define RED_STRIDE 68   // 68*4B=272 ≡ 0 mod 16 (b128-aligned), 2-way bank alias only

typedef __attribute__((ext_vector_type(8))) short short8;   // 8 x bf16 fragment
typedef __attribute__((ext_vector_type(4))) float float4v;

// ---------------- workspace layout (bytes) ----------------
#define OFF_CNT   0
#define OFF_Y0    1024
#define OFF_H1    (OFF_Y0 + 2*NB*NHID*2)          // y0 ring: 2 x [64][1024] bf16
#define OFF_XG    (OFF_H1 + 2*NB*NHID*2)          // h1 ring: 2 x [64][1024] bf16
#define OFF_T0    (OFF_XG + 2*3*NHID*NB*4)        // xg1 ring: 2 x [3072][64] f32
#define OFF_STATS (OFF_T0 + NVOC*3*NHID*4)        // T0: [31][3072] f32
#define OFF_Y1    (OFF_STATS + 2*NHID*4)          // y1: [512][64][1024] bf16 (64MB)

#define LDS_BYTES 64000

__device__ __forceinline__ unsigned short f2bf(float f){
  unsigned u = __builtin_bit_cast(unsigned, f);
  u += 0x7fffu + ((u >> 16) & 1u);               // RNE
  return (unsigned short)(u >> 16);
}
__device__ __forceinline__ float bf2f(unsigned short h){
  unsigned u = ((unsigned)h) << 16;
  return __builtin_bit_cast(float, u);
}
__device__ __forceinline__ float sigm(float x){ return 1.f/(1.f + __expf(-x)); }
__device__ __forceinline__ float tanh_f(float x){ return 1.f - 2.f/(__expf(2.f*x) + 1.f); }

// grid barrier: release(flush L2) -> arrive -> spin -> acquire(inv L2)
__device__ __forceinline__ void gbar(unsigned* cnt, unsigned target){
  __threadfence();          // each thread: waitcnt + wbl2 (release, agent scope)
  __syncthreads();          // all block stores now flushed
  if (threadIdx.x == 0){
    __hip_atomic_fetch_add(cnt, 1u, __ATOMIC_RELAXED, __HIP_MEMORY_SCOPE_AGENT);
    while (__hip_atomic_load(cnt, __ATOMIC_RELAXED, __HIP_MEMORY_SCOPE_AGENT) < target){
      __builtin_amdgcn_s_sleep(1);
    }
  }
  __syncthreads();
  __threadfence();          // acquire: invalidate stale L1/L2 lines
}

// [64,1024] bf16 (global) x Wslice^T (regs) -> partials reduced into red (LDS)
// wave `wid` owns K range [wid*128, wid*128+128). Two-stage reduce -> 4 partial sets.
__device__ __forceinline__ void gemm_phase(const unsigned short* H,
                                           const short8 (&bfr)[3][4],
                                           float* red, int lane, int wid)
{
  const int l15 = lane & 15, q = lane >> 4;
  float4v acc[4][3];
#pragma unroll
  for (int mt=0; mt<4; ++mt)
#pragma unroll
    for (int nt=0; nt<3; ++nt) acc[mt][nt] = (float4v){0.f,0.f,0.f,0.f};

  const unsigned short* base = H + (size_t)l15*NHID + wid*128 + q*8;
#pragma unroll
  for (int kt=0; kt<4; ++kt){
    short8 a0 = *(const short8*)(base + kt*32);
    short8 a1 = *(const short8*)(base + 16*NHID + kt*32);
    short8 a2 = *(const short8*)(base + 32*NHID + kt*32);
    short8 a3 = *(const short8*)(base + 48*NHID + kt*32);
#pragma unroll
    for (int nt=0; nt<3; ++nt){
      acc[0][nt] = __builtin_amdgcn_mfma_f32_16x16x32_bf16(a0, bfr[nt][kt], acc[0][nt],0,0,0);
      acc[1][nt] = __builtin_amdgcn_mfma_f32_16x16x32_bf16(a1, bfr[nt][kt], acc[1][nt],0,0,0);
      acc[2][nt] = __builtin_amdgcn_mfma_f32_16x16x32_bf16(a2, bfr[nt][kt], acc[2][nt],0,0,0);
      acc[3][nt] = __builtin_amdgcn_mfma_f32_16x16x32_bf16(a3, bfr[nt][kt], acc[3][nt],0,0,0);
    }
  }
  // two-stage cross-wave reduction (keeps LDS <= 52KB)
  if (wid >= 4){
#pragma unroll
    for (int mt=0; mt<4; ++mt)
#pragma unroll
      for (int nt=0; nt<3; ++nt){
        int n = nt*16 + l15, row = mt*16 + q*4;
        *(float4v*)(red + ((wid-4)*48 + n)*RED_STRIDE + row) = acc[mt][nt];
      }
  }
  __syncthreads();
  if (wid < 4){
#pragma unroll
    for (int mt=0; mt<4; ++mt)
#pragma unroll
      for (int nt=0; nt<3; ++nt){
        int n = nt*16 + l15, row = mt*16 + q*4;
        float4v* p = (float4v*)(red + (wid*48 + n)*RED_STRIDE + row);
        float4v v = *p;
        *p = v + acc[mt][nt];
      }
  }
  __syncthreads();
}

__device__ __forceinline__ void load_bfrags(const float* W, const int* rowbase,
                                            short8 (&bfr)[3][4], int lane, int wid)
{
  const int l15 = lane & 15, q = lane >> 4;
#pragma unroll
  for (int nt=0; nt<3; ++nt){
    const float* wp0 = W + (size_t)(rowbase[nt] + l15)*NHID + wid*128 + q*8;
#pragma unroll
    for (int kt=0; kt<4; ++kt){
      const float* wp = wp0 + kt*32;
      short8 f;
#pragma unroll
      for (int j=0;j<8;++j) f[j] = (short)f2bf(wp[j]);
      bfr[nt][kt] = f;
    }
  }
}

__global__ __launch_bounds__(NTHR) void mgru_fused(
    const int*   __restrict__ x,    const float* __restrict__ h0,
    const float* __restrict__ emb,
    const float* __restrict__ Wih0, const float* __restrict__ Whh0,
    const float* __restrict__ bih0, const float* __restrict__ bhh0,
    const float* __restrict__ Wih1, const float* __restrict__ Whh1,
    const float* __restrict__ bih1, const float* __restrict__ bhh1,
    const float* __restrict__ gamma, const float* __restrict__ beta,
    const float* __restrict__ Wout, const float* __restrict__ bout,
    float* __restrict__ out, char* ws)
{
  __shared__ __align__(16) char smem[LDS_BYTES];
  float* red = (float*)smem;

  unsigned*       cnt    = (unsigned*)(ws + OFF_CNT);
  unsigned short* y0ring = (unsigned short*)(ws + OFF_Y0);
  unsigned short* h1ring = (unsigned short*)(ws + OFF_H1);
  float*          xgring = (float*)(ws + OFF_XG);
  float*          T0     = (float*)(ws + OFF_T0);
  float*          stats  = (float*)(ws + OFF_STATS);
  unsigned short* y1     = (unsigned short*)(ws + OFF_Y1);

  const int tid  = threadIdx.x;
  const int lane = tid & 63;
  const int wid  = tid >> 6;
  const int wg   = blockIdx.x;
  const int role = (wg < 64) ? 0 : (wg < 128 ? 1 : 2);
  const int sub  = (role==0) ? wg : (role==1 ? wg-64 : wg-128);

  const int chl = tid & 15;
  const int b0  = tid >> 4;          // 0..31
  const int ch0 = sub*16;            // roles 0/2
  const int cb  = sub*48;            // role 1

  short8 bfr[3][4];
  int rowbase[3];
  float hprev0 = 0.f, hprev1 = 0.f;
  float s1 = 0.f, s2 = 0.f;
  float bias_r = 0.f, bias_z = 0.f, bias_n = 0.f;
  float bias6[6] = {0.f,0.f,0.f,0.f,0.f,0.f};

  // ---------------- preload / init ----------------
  if (role == 0){
    rowbase[0] = ch0; rowbase[1] = NHID + ch0; rowbase[2] = 2*NHID + ch0;
    bias_r = bhh0[ch0+chl]; bias_z = bhh0[NHID+ch0+chl]; bias_n = bhh0[2*NHID+ch0+chl];
    hprev0 = h0[(size_t)b0*NHID + ch0 + chl];
    hprev1 = h0[(size_t)(b0+32)*NHID + ch0 + chl];
    y0ring[(size_t)NB*NHID + (size_t)b0*NHID + ch0 + chl]      = f2bf(hprev0);
    y0ring[(size_t)NB*NHID + (size_t)(b0+32)*NHID + ch0 + chl] = f2bf(hprev1);
    // T0 slice: 31 x 48 dot products (one-time, fp32 VALU)
    for (int e = tid; e < NVOC*48; e += NTHR){
      int v = e / 48, n = e - v*48;
      int g = (n<16) ? (ch0+n) : (n<32 ? (NHID+ch0+n-16) : (2*NHID+ch0+n-32));
      const float4v* e4 = (const float4v*)(emb  + (size_t)v*NHID);
      const float4v* w4 = (const float4v*)(Wih0 + (size_t)g*NHID);
      float acc = 0.f;
      for (int k=0;k<NHID/4;++k){
        float4v a = e4[k], b = w4[k];
        acc += a[0]*b[0] + a[1]*b[1] + a[2]*b[2] + a[3]*b[3];
      }
      T0[(size_t)v*3*NHID + g] = acc + bih0[g];
    }
    load_bfrags(Whh0, rowbase, bfr, lane, wid);
  } else if (role == 1){
    rowbase[0] = cb; rowbase[1] = cb+16; rowbase[2] = cb+32;
#pragma unroll
    for (int i=0;i<6;++i){ int e = tid + i*NTHR; bias6[i] = bih1[cb + (e>>6)]; }
    load_bfrags(Wih1, rowbase, bfr, lane, wid);
  } else {
    rowbase[0] = ch0; rowbase[1] = NHID + ch0; rowbase[2] = 2*NHID + ch0;
    bias_r = bhh1[ch0+chl]; bias_z = bhh1[NHID+ch0+chl]; bias_n = bhh1[2*NHID+ch0+chl];
    hprev0 = h0[(size_t)NB*NHID + (size_t)b0*NHID + ch0 + chl];
    hprev1 = h0[(size_t)NB*NHID + (size_t)(b0+32)*NHID + ch0 + chl];
    h1ring[(size_t)NB*NHID + (size_t)b0*NHID + ch0 + chl]      = f2bf(hprev0);
    h1ring[(size_t)NB*NHID + (size_t)(b0+32)*NHID + ch0 + chl] = f2bf(hprev1);
    load_bfrags(Whh1, rowbase, bfr, lane, wid);
  }

  unsigned barnum = 0;
  gbar(cnt, (++barnum)*NBLK);

  // ---------------- pipelined recurrence: 514 phases ----------------
  for (int p = 0; p < NSEQ+2; ++p){
    int t; bool act;
    const unsigned short* Hsrc = nullptr;
    if (role == 0){ t = p;   act = (t < NSEQ); if (act) Hsrc = y0ring + (size_t)((t-1)&1)*NB*NHID; }
    else if (role == 1){ t = p-1; act = (t>=0 && t<NSEQ); if (act) Hsrc = y0ring + (size_t)(t&1)*NB*NHID; }
    else           { t = p-2; act = (t>=0 && t<NSEQ); if (act) Hsrc = h1ring + (size_t)((t-1)&1)*NB*NHID; }

    if (act){
      gemm_phase(Hsrc, bfr, red, lane, wid);
      if (role == 1){
        float* xw = xgring + (size_t)(t&1)*3*NHID*NB;
#pragma unroll
        for (int i=0;i<6;++i){
          int e = tid + i*NTHR;
          int nn = e >> 6, bb = e & 63;
          float v = bias6[i];
#pragma unroll
          for (int w=0;w<4;++w) v += red[(w*48+nn)*RED_STRIDE + bb];
          xw[(size_t)(cb + nn)*NB + bb] = v;
        }
      } else {
        const float* xgb = (role == 2) ? (xgring + (size_t)(t&1)*3*NHID*NB) : nullptr;
#pragma unroll
        for (int i=0;i<2;++i){
          int b = b0 + i*32;
          float hr = bias_r, hz = bias_z, hn = bias_n;
#pragma unroll
          for (int w=0;w<4;++w){
            hr += red[(w*48 +      chl)*RED_STRIDE + b];
            hz += red[(w*48 + 16 + chl)*RED_STRIDE + b];
            hn += red[(w*48 + 32 + chl)*RED_STRIDE + b];
          }
          float xr, xz, xn;
          if (role == 0){
            int tok = x[b*NSEQ + t];
            const float* tr = T0 + (size_t)tok*3*NHID;
            xr = tr[ch0+chl]; xz = tr[NHID+ch0+chl]; xn = tr[2*NHID+ch0+chl];
          } else {
            xr = xgb[(size_t)(ch0+chl)*NB + b];
            xz = xgb[(size_t)(NHID+ch0+chl)*NB + b];
            xn = xgb[(size_t)(2*NHID+ch0+chl)*NB + b];
          }
          float r = sigm(xr + hr);
          float z = sigm(xz + hz);
          float n = tanh_f(xn + r*hn);
          float hp = (i==0) ? hprev0 : hprev1;
          float hnew = (1.f - z)*n + z*hp;
          if (i==0) hprev0 = hnew; else hprev1 = hnew;
          unsigned short hb = f2bf(hnew);
          if (role == 0){
            y0ring[(size_t)(t&1)*NB*NHID + (size_t)b*NHID + ch0 + chl] = hb;
          } else {
            h1ring[(size_t)(t&1)*NB*NHID + (size_t)b*NHID + ch0 + chl] = hb;
            y1[(size_t)t*NB*NHID + (size_t)b*NHID + ch0 + chl] = hb;
            float hq = bf2f(hb);              // stats from stored value (self-consistent BN)
            s1 += hq; s2 += hq*hq;
          }
        }
      }
    }
    gbar(cnt, (++barnum)*NBLK);
  }

  // ---------------- BN stats ----------------
  if (role == 2){
    float* sb = (float*)smem;
    sb[tid] = s1; __syncthreads();
    float a1 = 0.f;
    if (tid < 16){ for (int j=0;j<32;++j) a1 += sb[tid + 16*j]; }
    __syncthreads();
    sb[tid] = s2; __syncthreads();
    float a2 = 0.f;
    if (tid < 16){ for (int j=0;j<32;++j) a2 += sb[tid + 16*j]; }
    if (tid < 16){ stats[ch0+tid] = a1; stats[NHID + ch0 + tid] = a2; }
  }
  gbar(cnt, (++barnum)*NBLK);

  // ---------------- epilogue: fold BN into Wout, GEMM -> out ----------------
  const float inv_n = 1.f/32768.f;
  const int l15 = lane & 15, q = lane >> 4;

  // b' = bout + sum_k (beta_k - mu_k*scale_k) * Wout[v,k]
  float* bpart    = (float*)smem;
  float* bprime_l = (float*)(smem + 2048);
  {
    int v = tid >> 4, k0 = tid & 15;
    float partial = 0.f;
    if (v < NVOC){
      for (int k = k0; k < NHID; k += 16){
        float mu  = stats[k]*inv_n;
        float var = stats[NHID+k]*inv_n - mu*mu;
        float sc  = gamma[k]*rsqrtf(var + EPSV);
        partial += (beta[k] - mu*sc) * Wout[(size_t)v*NHID + k];
      }
    }
    bpart[tid] = partial;
  }
  __syncthreads();
  if (tid < 32){
    float bp = 0.f;
    for (int j=0;j<16;++j) bp += bpart[tid*16 + j];
    bprime_l[tid] = (tid < NVOC) ? (bp + bout[tid]) : 0.f;
  }
  __syncthreads();
  float bp_a = bprime_l[l15];
  float bp_b = (l15 < 15) ? bprime_l[16 + l15] : 0.f;
  __syncthreads();

  // stage Wout' (bf16) in LDS: [31][1032] (pad -> 2-way banks only)
  unsigned short* wsc = (unsigned short*)smem;
  for (int e = tid; e < NVOC*1032; e += NTHR){
    int v = e / 1032, k = e - v*1032;
    float val = 0.f;
    if (k < NHID){
      float mu  = stats[k]*inv_n;
      float var = stats[NHID+k]*inv_n - mu*mu;
      float sc  = gamma[k]*rsqrtf(var + EPSV);
      val = Wout[(size_t)v*NHID + k] * sc;
    }
    wsc[e] = f2bf(val);
  }
  __syncthreads();

  // out = y1 @ Wout'^T + b'   (2048 M-tiles, 512 jobs of 4 tiles spread over all CUs)
  int wglob = wg*8 + wid;
  if ((wglob % 3) == 0){
    int J = wglob / 3;   // 0..511
    float4v acc[4][2];
#pragma unroll
    for (int mt=0;mt<4;++mt){ acc[mt][0] = (float4v){0,0,0,0}; acc[mt][1] = (float4v){0,0,0,0}; }
    const unsigned short* abase = y1 + (size_t)(J*64 + l15)*NHID + q*8;
    const short8 zero8 = (short8){0,0,0,0,0,0,0,0};
#pragma unroll 4
    for (int kt=0; kt<32; ++kt){
      short8 bv0 = *(const short8*)(wsc + (size_t)l15*1032 + kt*32 + q*8);
      short8 bv1 = (l15 < 15) ? *(const short8*)(wsc + (size_t)(16+l15)*1032 + kt*32 + q*8) : zero8;
      short8 a0 = *(const short8*)(abase + (size_t)kt*32);
      short8 a1 = *(const short8*)(abase + 16*NHID + (size_t)kt*32);
      short8 a2 = *(const short8*)(abase + 32*NHID + (size_t)kt*32);
      short8 a3 = *(const short8*)(abase + 48*NHID + (size_t)kt*32);
      acc[0][0] = __builtin_amdgcn_mfma_f32_16x16x32_bf16(a0, bv0, acc[0][0],0,0,0);
      acc[1][0] = __builtin_amdgcn_mfma_f32_16x16x32_bf16(a1, bv0, acc[1][0],0,0,0);
      acc[2][0] = __builtin_amdgcn_mfma_f32_16x16x32_bf16(a2, bv0, acc[2][0],0,0,0);
      acc[3][0] = __builtin_amdgcn_mfma_f32_16x16x32_bf16(a3, bv0, acc[3][0],0,0,0);
      acc[0][1] = __builtin_amdgcn_mfma_f32_16x16x32_bf16(a0, bv1, acc[0][1],0,0,0);
      acc[1][1] = __builtin_amdgcn_mfma_f32_16x16x32_bf16(a1, bv1, acc[1][1],0,0,0);
      acc[2][1] = __builtin_amdgcn_mfma_f32_16x16x32_bf16(a2, bv1, acc[2][1],0,0,0);
      acc[3][1] = __builtin_amdgcn_mfma_f32_16x16x32_bf16(a3, bv1, acc[3][1],0,0,0);
    }
#pragma unroll
    for (int mt=0;mt<4;++mt){
#pragma unroll
      for (int nt=0;nt<2;++nt){
        int v = nt*16 + l15;
        if (v < NVOC){
          float bp = (nt==0) ? bp_a : bp_b;
          int r0 = J*64 + mt*16 + q*4;
#pragma unroll
          for (int i2=0;i2<4;++i2){
            int r = r0 + i2;
            int b = r & 63, tt = r >> 6;
            out[(size_t)(b*NSEQ + tt)*NVOC + v] = acc[mt][nt][i2] + bp;
          }
        }
      }
    }
  }
}

extern "C" void kernel_launch(void* const* d_in, const int* in_sizes, int n_in,
                              void* d_out, int out_size, void* d_ws, size_t ws_size,
                              hipStream_t stream) {
  (void)in_sizes; (void)n_in; (void)out_size; (void)ws_size;
  // zero the barrier counter region (ws is poisoned 0xAA before every launch)
  hipMemsetAsync(d_ws, 0, 1024, stream);
  mgru_fused<<<dim3(NBLK), dim3(NTHR), 0, stream>>>(
      (const int*)d_in[0],  (const float*)d_in[1],  (const float*)d_in[2],
      (const float*)d_in[3], (const float*)d_in[4], (const float*)d_in[5],
      (const float*)d_in[6], (const float*)d_in[7], (const float*)d_in[8],
      (const float*)d_in[9], (const float*)d_in[10], (const float*)d_in[11],
      (const float*)d_in[12], (const float*)d_in[13], (const float*)d_in[14],
      (float*)d_out, (char*)d_ws);
}

// Round 2
// 9110.655 us; speedup vs baseline: 4.0525x; 4.0525x over previous
//
#include <hip/hip_runtime.h>
#include <cstddef>

// ---------------- problem constants ----------------
#define NHID 1024
#define NVOC 31
#define NB   64
#define NSEQ 512
#define NBLK 192     // 64 role0 + 64 role1 + 64 role2
#define NTHR 512     // 8 waves
#define EPSV 1e-5f
#define RS   68      // LDS reduce stride: 68*4B=272, 16B-aligned rows, 2-way bank alias only

typedef __attribute__((ext_vector_type(8))) short short8;   // 8 x bf16
typedef __attribute__((ext_vector_type(4))) float float4v;

// ---------------- workspace layout (bytes) ----------------
// counters: stride-16 uints (64B slots), one slot per timestep -> no ABA, no reuse
#define OFF_C0  0               // 513 slots: c0[0]=init, c0[t+1]=y0(t) ready (role0 done step t)
#define OFF_C1  32832           // 512 slots: c1[t] = role1 step t fully done (xg(t) written, y0(t) consumed)
#define OFF_C2  65600           // 513 slots: c2[0]=init, c2[t+1]=h1(t) ready
#define OFF_D2  98432           // 512 slots: d2[t] = role2 step t done (xg(t) consumed)
#define OFF_FIN 131200          // 1 slot
#define CNT_BYTES 131264
#define OFF_Y0  131328          // y0 ring: 2 x [64][1024] bf16
#define OFF_H1  393472          // h1 ring: 2 x [64][1024] bf16
#define OFF_XG  655616          // xg1 ring: 2 x [64][3072] f32
#define OFF_T0  2228480         // T0: [31][3072] f32 (role0-private)
#define OFF_ST  2609408         // stats: [2][1024] f32
#define OFF_Y1  2617600         // y1: [512][64][1024] bf16

#define LDS_BYTES 64000

__device__ __forceinline__ unsigned short f2bf(float f){
  unsigned u = __builtin_bit_cast(unsigned, f);
  u += 0x7fffu + ((u >> 16) & 1u);               // RNE
  return (unsigned short)(u >> 16);
}
__device__ __forceinline__ float bf2f(unsigned short h){
  unsigned u = ((unsigned)h) << 16;
  return __builtin_bit_cast(float, u);
}
__device__ __forceinline__ float sigm(float x){ return 1.f/(1.f + __expf(-x)); }
__device__ __forceinline__ float tanh_f(float x){ return 1.f - 2.f/(__expf(2.f*x) + 1.f); }

// ---- coherent (cache-bypassing) data plane: relaxed agent-scope atomics ----
__device__ __forceinline__ unsigned long long ld8(const void* p){
  return __hip_atomic_load((const unsigned long long*)p, __ATOMIC_RELAXED, __HIP_MEMORY_SCOPE_AGENT);
}
__device__ __forceinline__ void st8(void* p, unsigned long long v){
  __hip_atomic_store((unsigned long long*)p, v, __ATOMIC_RELAXED, __HIP_MEMORY_SCOPE_AGENT);
}
__device__ __forceinline__ float ldf(const void* p){
  return __hip_atomic_load((const float*)p, __ATOMIC_RELAXED, __HIP_MEMORY_SCOPE_AGENT);
}
__device__ __forceinline__ void stf(void* p, float v){
  __hip_atomic_store((float*)p, v, __ATOMIC_RELAXED, __HIP_MEMORY_SCOPE_AGENT);
}
__device__ __forceinline__ void sig(unsigned* c){
  __hip_atomic_fetch_add(c, 1u, __ATOMIC_RELAXED, __HIP_MEMORY_SCOPE_AGENT);
}
__device__ __forceinline__ void waitc(unsigned* c, unsigned v){
  while (__hip_atomic_load(c, __ATOMIC_RELAXED, __HIP_MEMORY_SCOPE_AGENT) < v)
    __builtin_amdgcn_s_sleep(2);
}

union U16x8 { unsigned long long u[2]; short8 v; };
__device__ __forceinline__ short8 ld_frag(const unsigned short* p){
  U16x8 t; t.u[0] = ld8(p); t.u[1] = ld8(p + 4); return t.v;
}
union F2U { float f[2]; unsigned long long u; };
__device__ __forceinline__ unsigned long long packf2(float a, float b){
  F2U t; t.f[0] = a; t.f[1] = b; return t.u;
}
__device__ __forceinline__ unsigned long long packbf4(float a, float b, float c, float d){
  return (unsigned long long)f2bf(a) | ((unsigned long long)f2bf(b) << 16)
       | ((unsigned long long)f2bf(c) << 32) | ((unsigned long long)f2bf(d) << 48);
}

// H [64,1024] bf16 (coherent loads) x Wslice^T (regs) -> partials summed into red (LDS).
// wave wid owns K in [wid*128, wid*128+128). Two-stage reduce -> 4 partial sets remain.
__device__ __forceinline__ void gemm_phase(const unsigned short* H,
                                           const short8 (&bfr)[3][4],
                                           float* red, int lane, int wid)
{
  const int l15 = lane & 15, q = lane >> 4;
  float4v acc[4][3];
#pragma unroll
  for (int mt=0; mt<4; ++mt)
#pragma unroll
    for (int nt=0; nt<3; ++nt) acc[mt][nt] = (float4v){0.f,0.f,0.f,0.f};

  const unsigned short* base = H + (size_t)l15*NHID + wid*128 + q*8;
#pragma unroll
  for (int kt=0; kt<4; ++kt){
    short8 a0 = ld_frag(base + kt*32);
    short8 a1 = ld_frag(base + 16*NHID + kt*32);
    short8 a2 = ld_frag(base + 32*NHID + kt*32);
    short8 a3 = ld_frag(base + 48*NHID + kt*32);
#pragma unroll
    for (int nt=0; nt<3; ++nt){
      acc[0][nt] = __builtin_amdgcn_mfma_f32_16x16x32_bf16(a0, bfr[nt][kt], acc[0][nt],0,0,0);
      acc[1][nt] = __builtin_amdgcn_mfma_f32_16x16x32_bf16(a1, bfr[nt][kt], acc[1][nt],0,0,0);
      acc[2][nt] = __builtin_amdgcn_mfma_f32_16x16x32_bf16(a2, bfr[nt][kt], acc[2][nt],0,0,0);
      acc[3][nt] = __builtin_amdgcn_mfma_f32_16x16x32_bf16(a3, bfr[nt][kt], acc[3][nt],0,0,0);
    }
  }
  if (wid >= 4){
#pragma unroll
    for (int mt=0; mt<4; ++mt)
#pragma unroll
      for (int nt=0; nt<3; ++nt){
        int n = nt*16 + l15, row = mt*16 + q*4;
        *(float4v*)(red + ((wid-4)*48 + n)*RS + row) = acc[mt][nt];
      }
  }
  __syncthreads();
  if (wid < 4){
#pragma unroll
    for (int mt=0; mt<4; ++mt)
#pragma unroll
      for (int nt=0; nt<3; ++nt){
        int n = nt*16 + l15, row = mt*16 + q*4;
        float4v* p = (float4v*)(red + (wid*48 + n)*RS + row);
        float4v v = *p;
        *p = v + acc[mt][nt];
      }
  }
  __syncthreads();
}

__device__ __forceinline__ void load_bfrags(const float* W, const int* rowbase,
                                            short8 (&bfr)[3][4], int lane, int wid)
{
  const int l15 = lane & 15, q = lane >> 4;
#pragma unroll
  for (int nt=0; nt<3; ++nt){
    const float* wp0 = W + (size_t)(rowbase[nt] + l15)*NHID + wid*128 + q*8;
#pragma unroll
    for (int kt=0; kt<4; ++kt){
      const float* wp = wp0 + kt*32;
      short8 f;
#pragma unroll
      for (int j=0;j<8;++j) f[j] = (short)f2bf(wp[j]);
      bfr[nt][kt] = f;
    }
  }
}

__global__ __launch_bounds__(NTHR) void mgru_fused(
    const int*   __restrict__ x,    const float* __restrict__ h0,
    const float* __restrict__ emb,
    const float* __restrict__ Wih0, const float* __restrict__ Whh0,
    const float* __restrict__ bih0, const float* __restrict__ bhh0,
    const float* __restrict__ Wih1, const float* __restrict__ Whh1,
    const float* __restrict__ bih1, const float* __restrict__ bhh1,
    const float* __restrict__ gamma, const float* __restrict__ beta,
    const float* __restrict__ Wout, const float* __restrict__ bout,
    float* __restrict__ out, char* ws)
{
  __shared__ __align__(16) char smem[LDS_BYTES];
  float* red = (float*)smem;

  unsigned* c0  = (unsigned*)(ws + OFF_C0);
  unsigned* c1  = (unsigned*)(ws + OFF_C1);
  unsigned* c2  = (unsigned*)(ws + OFF_C2);
  unsigned* d2  = (unsigned*)(ws + OFF_D2);
  unsigned* fin = (unsigned*)(ws + OFF_FIN);
  unsigned short* y0ring = (unsigned short*)(ws + OFF_Y0);
  unsigned short* h1ring = (unsigned short*)(ws + OFF_H1);
  float*          xgring = (float*)(ws + OFF_XG);
  float*          T0     = (float*)(ws + OFF_T0);
  float*          stats  = (float*)(ws + OFF_ST);
  unsigned short* y1     = (unsigned short*)(ws + OFF_Y1);

  const int tid  = threadIdx.x;
  const int lane = tid & 63;
  const int wid  = tid >> 6;
  const int wg   = blockIdx.x;
  const int role = (wg < 64) ? 0 : (wg < 128 ? 1 : 2);
  const int sub  = (role==0) ? wg : (role==1 ? wg-64 : wg-128);

  short8 bfr[3][4];
  int rowbase[3];

  if (role == 0){
    // ================= layer-0 recurrence =================
    const int ch0 = sub*16;
    const int cq = wid, b = lane;     // gate thread mapping (tid<256): wave=channel-quad, lane=batch
    float hprev[4] = {0,0,0,0};
    float br[4], bz[4], bn[4];
    if (tid < 256){
#pragma unroll
      for (int j=0;j<4;++j){
        hprev[j] = h0[(size_t)b*NHID + ch0 + cq*4 + j];
        br[j] = bhh0[ch0 + cq*4 + j];
        bz[j] = bhh0[NHID + ch0 + cq*4 + j];
        bn[j] = bhh0[2*NHID + ch0 + cq*4 + j];
      }
      st8(y0ring + (size_t)NB*NHID + (size_t)b*NHID + ch0 + cq*4,
          packbf4(hprev[0],hprev[1],hprev[2],hprev[3]));
    }
    __syncthreads();                       // drain init stores (vmcnt(0) before barrier)
    if (tid == 0) sig(c0);                 // c0[0]: this WG's h0 slice visible

    // T0 slice: 31 x 48 dot products (role0-private, plain cached)
    for (int e = tid; e < NVOC*48; e += NTHR){
      int v = e / 48, n = e - v*48;
      int g = (n<16) ? (ch0+n) : (n<32 ? (NHID+ch0+n-16) : (2*NHID+ch0+n-32));
      const float4v* e4 = (const float4v*)(emb  + (size_t)v*NHID);
      const float4v* w4 = (const float4v*)(Wih0 + (size_t)g*NHID);
      float acc = 0.f;
      for (int k=0;k<NHID/4;++k){
        float4v a = e4[k], bb = w4[k];
        acc += a[0]*bb[0] + a[1]*bb[1] + a[2]*bb[2] + a[3]*bb[3];
      }
      T0[(size_t)v*3*NHID + g] = acc + bih0[g];
    }
    rowbase[0] = ch0; rowbase[1] = NHID + ch0; rowbase[2] = 2*NHID + ch0;
    load_bfrags(Whh0, rowbase, bfr, lane, wid);
    __syncthreads();                       // T0 visible to whole WG

    for (int t = 0; t < NSEQ; ++t){
      if (tid == 0){
        waitc(c0 + (size_t)t*16, 64);                    // y0(t-1) ready (or init)
        if (t >= 2) waitc(c1 + (size_t)(t-2)*16, 64);    // WAR: role1 consumed y0(t-2)
      }
      __syncthreads();
      gemm_phase(y0ring + (size_t)((t+1)&1)*NB*NHID, bfr, red, lane, wid);
      if (tid < 256){
        int tok = x[(size_t)b*NSEQ + t];
        const float* tr = T0 + (size_t)tok*3*NHID + ch0 + cq*4;
        float hv[4];
#pragma unroll
        for (int j=0;j<4;++j){
          float hr = br[j], hz = bz[j], hn = bn[j];
#pragma unroll
          for (int w=0;w<4;++w){
            hr += red[(w*48 + cq*4 + j)*RS + b];
            hz += red[(w*48 + 16 + cq*4 + j)*RS + b];
            hn += red[(w*48 + 32 + cq*4 + j)*RS + b];
          }
          float r = sigm(tr[j] + hr);
          float z = sigm(tr[NHID + j] + hz);
          float n = tanh_f(tr[2*NHID + j] + r*hn);
          float hnv = (1.f - z)*n + z*hprev[j];
          hprev[j] = hnv; hv[j] = hnv;
        }
        st8(y0ring + (size_t)(t&1)*NB*NHID + (size_t)b*NHID + ch0 + cq*4,
            packbf4(hv[0],hv[1],hv[2],hv[3]));
      }
      __syncthreads();                     // drain h stores
      if (tid == 0) sig(c0 + (size_t)(t+1)*16);
    }
    __syncthreads();
    if (tid == 0) sig(fin);

  } else if (role == 1){
    // ================= xg1 = y0 @ Wih1^T =================
    const int cb = sub*48;
    const int b = lane;
    float bq[2][4];
#pragma unroll
    for (int j=0;j<4;++j) bq[0][j] = bih1[cb + wid*4 + j];
    if (wid < 4){
#pragma unroll
      for (int j=0;j<4;++j) bq[1][j] = bih1[cb + 32 + wid*4 + j];
    }
    rowbase[0] = cb; rowbase[1] = cb+16; rowbase[2] = cb+32;
    load_bfrags(Wih1, rowbase, bfr, lane, wid);
    __syncthreads();

    const int npass = (wid < 4) ? 2 : 1;
    for (int t = 0; t < NSEQ; ++t){
      if (tid == 0){
        waitc(c0 + (size_t)(t+1)*16, 64);                // y0(t) ready
        if (t >= 2) waitc(d2 + (size_t)(t-2)*16, 64);    // WAR: role2 consumed xg(t-2)
      }
      __syncthreads();
      gemm_phase(y0ring + (size_t)(t&1)*NB*NHID, bfr, red, lane, wid);
      float* xgs = xgring + (size_t)(t&1)*NB*3*NHID + (size_t)b*3*NHID;
      for (int pass = 0; pass < npass; ++pass){
        int nq = pass ? (8 + wid) : wid;
        float v[4];
#pragma unroll
        for (int j=0;j<4;++j){
          float s = bq[pass][j];
#pragma unroll
          for (int w=0;w<4;++w) s += red[(w*48 + nq*4 + j)*RS + b];
          v[j] = s;
        }
        st8(xgs + cb + nq*4,     packf2(v[0], v[1]));
        st8(xgs + cb + nq*4 + 2, packf2(v[2], v[3]));
      }
      __syncthreads();                     // drain xg stores (+ red reads done)
      if (tid == 0) sig(c1 + (size_t)t*16);
    }
    __syncthreads();
    if (tid == 0) sig(fin);

  } else {
    // ================= layer-1 recurrence + BN stats =================
    const int ch0 = sub*16;
    const int cq = wid, b = lane;
    float hprev[4] = {0,0,0,0};
    float br[4], bz[4], bn[4];
    float s1[4] = {0,0,0,0}, s2[4] = {0,0,0,0};
    if (tid < 256){
#pragma unroll
      for (int j=0;j<4;++j){
        hprev[j] = h0[(size_t)NB*NHID + (size_t)b*NHID + ch0 + cq*4 + j];
        br[j] = bhh1[ch0 + cq*4 + j];
        bz[j] = bhh1[NHID + ch0 + cq*4 + j];
        bn[j] = bhh1[2*NHID + ch0 + cq*4 + j];
      }
      st8(h1ring + (size_t)NB*NHID + (size_t)b*NHID + ch0 + cq*4,
          packbf4(hprev[0],hprev[1],hprev[2],hprev[3]));
    }
    __syncthreads();
    if (tid == 0) sig(c2);                 // c2[0]
    rowbase[0] = ch0; rowbase[1] = NHID + ch0; rowbase[2] = 2*NHID + ch0;
    load_bfrags(Whh1, rowbase, bfr, lane, wid);
    __syncthreads();

    for (int t = 0; t < NSEQ; ++t){
      if (tid == 0){
        waitc(c1 + (size_t)t*16, 64);      // xg(t) ready
        waitc(c2 + (size_t)t*16, 64);      // h1(t-1) ready (or init)
      }
      __syncthreads();
      gemm_phase(h1ring + (size_t)((t+1)&1)*NB*NHID, bfr, red, lane, wid);
      if (tid < 256){
        const float* xgs = xgring + (size_t)(t&1)*NB*3*NHID + (size_t)b*3*NHID + ch0 + cq*4;
        F2U xr0, xr1, xz0, xz1, xn0, xn1;
        xr0.u = ld8(xgs);            xr1.u = ld8(xgs + 2);
        xz0.u = ld8(xgs + NHID);     xz1.u = ld8(xgs + NHID + 2);
        xn0.u = ld8(xgs + 2*NHID);   xn1.u = ld8(xgs + 2*NHID + 2);
        float xr[4] = {xr0.f[0], xr0.f[1], xr1.f[0], xr1.f[1]};
        float xz[4] = {xz0.f[0], xz0.f[1], xz1.f[0], xz1.f[1]};
        float xn[4] = {xn0.f[0], xn0.f[1], xn1.f[0], xn1.f[1]};
        unsigned long long pk = 0;
#pragma unroll
        for (int j=0;j<4;++j){
          float hr = br[j], hz = bz[j], hn = bn[j];
#pragma unroll
          for (int w=0;w<4;++w){
            hr += red[(w*48 + cq*4 + j)*RS + b];
            hz += red[(w*48 + 16 + cq*4 + j)*RS + b];
            hn += red[(w*48 + 32 + cq*4 + j)*RS + b];
          }
          float r = sigm(xr[j] + hr);
          float z = sigm(xz[j] + hz);
          float n = tanh_f(xn[j] + r*hn);
          float hnv = (1.f - z)*n + z*hprev[j];
          hprev[j] = hnv;
          unsigned short hb = f2bf(hnv);
          pk |= ((unsigned long long)hb) << (16*j);
          float hq = bf2f(hb);               // BN stats from stored bf16 (self-consistent)
          s1[j] += hq; s2[j] += hq*hq;
        }
        st8(h1ring + (size_t)(t&1)*NB*NHID + (size_t)b*NHID + ch0 + cq*4, pk);
        st8(y1 + (size_t)t*NB*NHID + (size_t)b*NHID + ch0 + cq*4, pk);
      }
      __syncthreads();
      if (tid == 0){ sig(c2 + (size_t)(t+1)*16); sig(d2 + (size_t)t*16); }
    }

    // BN stats: reduce per channel over 64 lanes, write coherent
    float* sb = (float*)smem;
    __syncthreads();
    if (tid < 256){
#pragma unroll
      for (int j=0;j<4;++j) sb[(cq*4 + j)*64 + b] = s1[j];
    }
    __syncthreads();
    if (tid < 16){
      float a = 0.f;
      for (int i=0;i<64;++i) a += sb[tid*64 + i];
      stf(stats + ch0 + tid, a);
    }
    __syncthreads();
    if (tid < 256){
#pragma unroll
      for (int j=0;j<4;++j) sb[(cq*4 + j)*64 + b] = s2[j];
    }
    __syncthreads();
    if (tid < 16){
      float a = 0.f;
      for (int i=0;i<64;++i) a += sb[tid*64 + i];
      stf(stats + NHID + ch0 + tid, a);
    }
    __syncthreads();                       // drain stat stores
    if (tid == 0) sig(fin);
  }

  // ================= global finish barrier =================
  if (tid == 0) waitc(fin, NBLK);
  __syncthreads();

  // ================= epilogue: fold BN into Wout, GEMM -> out =================
  const float inv_n = 1.f/32768.f;
  const int l15 = lane & 15, q = lane >> 4;

  float* bpart    = (float*)smem;
  float* bprime_l = (float*)(smem + 2048);
  {
    int v = tid >> 4, k0 = tid & 15;
    float partial = 0.f;
    if (v < NVOC){
      for (int k = k0; k < NHID; k += 16){
        float mu  = ldf(stats + k)*inv_n;
        float var = ldf(stats + NHID + k)*inv_n - mu*mu;
        float sc  = gamma[k]*rsqrtf(var + EPSV);
        partial += (beta[k] - mu*sc) * Wout[(size_t)v*NHID + k];
      }
    }
    bpart[tid] = partial;
  }
  __syncthreads();
  if (tid < 32){
    float bp = 0.f;
    for (int j=0;j<16;++j) bp += bpart[tid*16 + j];
    bprime_l[tid] = (tid < NVOC) ? (bp + bout[tid]) : 0.f;
  }
  __syncthreads();
  float bp_a = bprime_l[l15];
  float bp_b = (l15 < 15) ? bprime_l[16 + l15] : 0.f;
  __syncthreads();

  unsigned short* wsc = (unsigned short*)smem;   // [31][1032] bf16
  for (int e = tid; e < NVOC*1032; e += NTHR){
    int v = e / 1032, k = e - v*1032;
    float val = 0.f;
    if (k < NHID){
      float mu  = ldf(stats + k)*inv_n;
      float var = ldf(stats + NHID + k)*inv_n - mu*mu;
      float sc  = gamma[k]*rsqrtf(var + EPSV);
      val = Wout[(size_t)v*NHID + k] * sc;
    }
    wsc[e] = f2bf(val);
  }
  __syncthreads();

  int wglob = wg*8 + wid;
  if ((wglob % 3) == 0){
    int J = wglob / 3;   // 0..511, each = 64 rows of the 32768-row output
    float4v acc[4][2];
#pragma unroll
    for (int mt=0;mt<4;++mt){ acc[mt][0] = (float4v){0,0,0,0}; acc[mt][1] = (float4v){0,0,0,0}; }
    const unsigned short* abase = y1 + (size_t)(J*64 + l15)*NHID + q*8;
    const short8 zero8 = (short8){0,0,0,0,0,0,0,0};
#pragma unroll 4
    for (int kt=0; kt<32; ++kt){
      short8 bv0 = *(const short8*)(wsc + (size_t)l15*1032 + kt*32 + q*8);
      short8 bv1 = (l15 < 15) ? *(const short8*)(wsc + (size_t)(16+l15)*1032 + kt*32 + q*8) : zero8;
      short8 a0 = *(const short8*)(abase + (size_t)kt*32);
      short8 a1 = *(const short8*)(abase + 16*NHID + (size_t)kt*32);
      short8 a2 = *(const short8*)(abase + 32*NHID + (size_t)kt*32);
      short8 a3 = *(const short8*)(abase + 48*NHID + (size_t)kt*32);
      acc[0][0] = __builtin_amdgcn_mfma_f32_16x16x32_bf16(a0, bv0, acc[0][0],0,0,0);
      acc[1][0] = __builtin_amdgcn_mfma_f32_16x16x32_bf16(a1, bv0, acc[1][0],0,0,0);
      acc[2][0] = __builtin_amdgcn_mfma_f32_16x16x32_bf16(a2, bv0, acc[2][0],0,0,0);
      acc[3][0] = __builtin_amdgcn_mfma_f32_16x16x32_bf16(a3, bv0, acc[3][0],0,0,0);
      acc[0][1] = __builtin_amdgcn_mfma_f32_16x16x32_bf16(a0, bv1, acc[0][1],0,0,0);
      acc[1][1] = __builtin_amdgcn_mfma_f32_16x16x32_bf16(a1, bv1, acc[1][1],0,0,0);
      acc[2][1] = __builtin_amdgcn_mfma_f32_16x16x32_bf16(a2, bv1, acc[2][1],0,0,0);
      acc[3][1] = __builtin_amdgcn_mfma_f32_16x16x32_bf16(a3, bv1, acc[3][1],0,0,0);
    }
#pragma unroll
    for (int mt=0;mt<4;++mt){
#pragma unroll
      for (int nt=0;nt<2;++nt){
        int v = nt*16 + l15;
        if (v < NVOC){
          float bp = (nt==0) ? bp_a : bp_b;
          int r0 = J*64 + mt*16 + q*4;
#pragma unroll
          for (int i2=0;i2<4;++i2){
            int r = r0 + i2;
            int b = r & 63, tt = r >> 6;
            out[(size_t)(b*NSEQ + tt)*NVOC + v] = acc[mt][nt][i2] + bp;
          }
        }
      }
    }
  }
}

extern "C" void kernel_launch(void* const* d_in, const int* in_sizes, int n_in,
                              void* d_out, int out_size, void* d_ws, size_t ws_size,
                              hipStream_t stream) {
  (void)in_sizes; (void)n_in; (void)out_size; (void)ws_size;
  hipMemsetAsync(d_ws, 0, CNT_BYTES, stream);   // zero all sync counters
  mgru_fused<<<dim3(NBLK), dim3(NTHR), 0, stream>>>(
      (const int*)d_in[0],  (const float*)d_in[1],  (const float*)d_in[2],
      (const float*)d_in[3], (const float*)d_in[4], (const float*)d_in[5],
      (const float*)d_in[6], (const float*)d_in[7], (const float*)d_in[8],
      (const float*)d_in[9], (const float*)d_in[10], (const float*)d_in[11],
      (const float*)d_in[12], (const float*)d_in[13], (const float*)d_in[14],
      (float*)d_out, (char*)d_ws);
}